// Round 14
// baseline (89.978 us; speedup 1.0000x reference)
//
#include <hip/hip_runtime.h>

typedef __attribute__((ext_vector_type(8)))  short s16x8;
typedef __attribute__((ext_vector_type(4)))  float f32x4;
typedef __attribute__((ext_vector_type(16))) float f32x16;
typedef __attribute__((ext_vector_type(4)))  unsigned int u32x4;

#define CHN 512
#define NSP 4096

__device__ __forceinline__ ushort f2b(float f){
  unsigned u = __builtin_bit_cast(unsigned, f);
  u = (u + 0x7fffu + ((u >> 16) & 1u)) >> 16;
  return (ushort)u;
}
__device__ __forceinline__ float b2f(ushort u){
  return __builtin_bit_cast(float, ((unsigned)u) << 16);
}

__device__ __forceinline__ s16x8 ldfrag(const void* p){
  return *reinterpret_cast<const s16x8*>(p);
}

__device__ __forceinline__ f32x4 mfma16(s16x8 a, s16x8 b, f32x4 c){
  return __builtin_amdgcn_mfma_f32_16x16x32_bf16(a, b, c, 0, 0, 0);
}
__device__ __forceinline__ f32x16 mfma32(s16x8 a, s16x8 b, f32x16 c){
  return __builtin_amdgcn_mfma_f32_32x32x16_bf16(a, b, c, 0, 0, 0);
}
__device__ __forceinline__ unsigned cvtpk(float lo, float hi){
  unsigned r;
  asm("v_cvt_pk_bf16_f32 %0, %1, %2" : "=v"(r) : "v"(lo), "v"(hi));
  return r;
}
__device__ __forceinline__ void gload16(const void* g, void* l){
  __builtin_amdgcn_global_load_lds(
      (const __attribute__((address_space(1))) unsigned int*)g,
      (__attribute__((address_space(3))) unsigned int*)l, 16, 0, 0);
}
__device__ __forceinline__ ushort4 f4b(float4 v){
  ushort4 o;
  o.x = f2b(v.x); o.y = f2b(v.y); o.z = f2b(v.z); o.w = f2b(v.w);
  return o;
}

// ---------- fused preprocessing: weight cvt (qkv, proj) + group-norm partials ----------
__global__ __launch_bounds__(256) void prep(const float4* __restrict__ qkvw, const float4* __restrict__ projw,
                                            const float* __restrict__ x,
                                            ushort4* __restrict__ Wq, ushort4* __restrict__ Wp,
                                            float* __restrict__ part){
  int b = blockIdx.x;
  if (b < 768){
    int i = b*256 + threadIdx.x;
    Wq[i] = f4b(qkvw[i]);
  } else if (b < 1024){
    int i = (b-768)*256 + threadIdx.x;
    Wp[i] = f4b(projw[i]);
  } else {
    int pb = b - 1024;
    const float4* p = reinterpret_cast<const float4*>(x + (size_t)pb * 8192);
    float s = 0.f, s2 = 0.f;
    #pragma unroll
    for (int i = 0; i < 8; ++i){
      float4 v = p[threadIdx.x + i*256];
      s  += v.x + v.y + v.z + v.w;
      s2 += v.x*v.x + v.y*v.y + v.z*v.z + v.w*v.w;
    }
    #pragma unroll
    for (int off = 32; off > 0; off >>= 1){ s += __shfl_down(s, off); s2 += __shfl_down(s2, off); }
    __shared__ float ls[4], ls2[4];
    int wv = threadIdx.x >> 6;
    if ((threadIdx.x & 63) == 0){ ls[wv] = s; ls2[wv] = s2; }
    __syncthreads();
    if (threadIdx.x == 0){
      part[pb*2]     = ls[0]+ls[1]+ls[2]+ls[3];
      part[pb*2 + 1] = ls2[0]+ls2[1]+ls2[2]+ls2[3];
    }
  }
}

// ---------- fused gn-final + norm + SiLU + transpose: x (C,N) fp32 -> h_t (N,C) bf16 ----------
__global__ __launch_bounds__(256) void norm_apply(const float* __restrict__ x, const float* __restrict__ part,
                                                  const float* __restrict__ nw, const float* __restrict__ nb,
                                                  ushort* __restrict__ h_t){
  __shared__ float tile[64][65];
  __shared__ float smu[32], srs[32];
  if (threadIdx.x < 32){
    int g = threadIdx.x;
    float s = 0.f, s2 = 0.f;
    #pragma unroll
    for (int i = 0; i < 8; ++i){ s += part[(g*8+i)*2]; s2 += part[(g*8+i)*2+1]; }
    float mu  = s * (1.f/65536.f);
    float var = s2 * (1.f/65536.f) - mu*mu;
    smu[g] = mu;
    srs[g] = rsqrtf(var + 1e-5f);
  }
  __syncthreads();
  int ct0 = (blockIdx.x >> 6) << 6;
  int nt0 = (blockIdx.x & 63) << 6;
  int tc = threadIdx.x >> 6;
  int tn = threadIdx.x & 63;
  #pragma unroll
  for (int rr = 0; rr < 16; ++rr){
    int cl = rr*4 + tc;
    int c  = ct0 + cl;
    float v  = x[(size_t)c * NSP + nt0 + tn];
    float hn = (v - smu[c >> 4]) * srs[c >> 4] * nw[c] + nb[c];
    float sv = hn / (1.f + __expf(-hn));
    tile[tn][cl] = sv;
  }
  __syncthreads();
  #pragma unroll
  for (int rr = 0; rr < 16; ++rr){
    int nl = rr*4 + tc;
    h_t[(size_t)(nt0 + nl) * CHN + ct0 + tn] = f2b(tile[nl][tn]);
  }
}

// ---------- GEMM: C(n,o) = A(n,c) * Bw(o,c)^T, LDS-staged 2-phase ----------
template<int MODE, int BM, int BN>
__global__ __launch_bounds__(256) void gemm_tn(
    const ushort* __restrict__ A, const ushort* __restrict__ Bw,
    const float* __restrict__ bias, const float* __restrict__ xres,
    ushort* __restrict__ qS, ushort* __restrict__ kF, ushort* __restrict__ vF,
    float* __restrict__ outF)
{
  constexpr int RW = BM/2, CW = BN/2;
  constexpr int MI = RW/16, NJ = CW/16;
  __shared__ __align__(16) ushort As[2][BM*32];
  __shared__ __align__(16) ushort Bs[2][BN*32];
  int tid = threadIdx.x;
  int lane = tid & 63, wv = tid >> 6;
  int lr = lane & 15, lg = lane >> 4;
  int wr = wv >> 1, wc = wv & 1;
  int nbB = blockIdx.x * BM;
  int obB = blockIdx.y * BN;
  int nb = nbB + wr*RW, ob = obB + wc*CW;
  f32x4 acc[MI][NJ] = {};

  const ushort* Ag = A  + (size_t)(nbB + (tid>>2))*CHN + (tid&3)*8;
  const ushort* Bg = Bw + (size_t)(obB + (tid>>2))*CHN + (tid&3)*8;

  #define GSTAGE(BUF, KK) {                                                    \
    _Pragma("unroll") for (int ii = 0; ii < BM/64; ++ii)                       \
      gload16(Ag + (size_t)ii*64*CHN + (KK), &As[BUF][ii*2048 + tid*8]);       \
    _Pragma("unroll") for (int ii = 0; ii < BN/64; ++ii)                       \
      gload16(Bg + (size_t)ii*64*CHN + (KK), &Bs[BUF][ii*2048 + tid*8]); }

  GSTAGE(0, 0);
  asm volatile("s_waitcnt vmcnt(0)" ::: "memory");
  __syncthreads();
  int cur = 0;
  for (int kk = 0; kk < CHN; kk += 32){
    if (kk < CHN-32) GSTAGE(cur^1, kk+32);
    s16x8 af[MI], bf[NJ];
    #pragma unroll
    for (int t = 0; t < MI; ++t) af[t] = *(const s16x8*)&As[cur][(wr*RW + lr + t*16)*32 + lg*8];
    #pragma unroll
    for (int t = 0; t < NJ; ++t) bf[t] = *(const s16x8*)&Bs[cur][(wc*CW + lr + t*16)*32 + lg*8];
    #pragma unroll
    for (int i = 0; i < MI; ++i)
      #pragma unroll
      for (int j = 0; j < NJ; ++j)
        acc[i][j] = mfma16(af[i], bf[j], acc[i][j]);
    asm volatile("s_waitcnt vmcnt(0)" ::: "memory");
    __syncthreads();
    cur ^= 1;
  }
  #undef GSTAGE

  if (MODE == 0){
    #pragma unroll
    for (int j = 0; j < NJ; ++j){
      int o = ob + j*16 + lr;
      float bs = bias[o];
      int sec = o >> 9;        // 0=Q 1=K 2=V  (uniform per wave)
      int co  = o & 511;
      int bb = co >> 6, dd = co & 63;
      if (sec == 0){
        const float qsc = 0.18033688011112042f;  // 0.125*log2(e)
        #pragma unroll
        for (int i = 0; i < MI; ++i){
          int n0 = nb + i*16 + lg*4;
          int hh = n0 >> 9, aa = n0 & 511;
          size_t base = ((size_t)((hh<<3)+bb)*512 + aa)*64 + dd;
          #pragma unroll
          for (int r = 0; r < 4; ++r)
            qS[base + (size_t)r*64] = f2b((acc[i][j][r] + bs) * qsc);
        }
      } else if (sec == 1){
        int s = dd >> 4, khi = (dd >> 3) & 1, off = dd & 7;
        #pragma unroll
        for (int i = 0; i < MI; ++i){
          int n0 = nb + i*16 + lg*4;
          int hh = n0 >> 9, aa = n0 & 511;
          int T = bb*16 + (aa >> 5);
          size_t widx = ((((size_t)hh*128 + T)*4 + s)*64 + (aa & 31) + 32*khi)*8 + off;
          #pragma unroll
          for (int r = 0; r < 4; ++r)
            kF[widx + (size_t)r*8] = f2b(acc[i][j][r] + bs);
        }
      } else {
        int l31v = dd & 31, fh = dd >> 5;
        #pragma unroll
        for (int i = 0; i < MI; ++i){
          int n0 = nb + i*16 + lg*4;
          int hh = n0 >> 9, aa = n0 & 511;
          int T = bb*16 + (aa >> 5);
          int w = aa & 31;
          int f = fh*2 + (w >> 4);
          int vhi = (w >> 3) & 1, koff = w & 7;
          size_t widx = ((((size_t)hh*128 + T)*4 + f)*64 + l31v + 32*vhi)*8 + koff;
          ushort4 pk;
          pk.x = f2b(acc[i][j][0] + bs);
          pk.y = f2b(acc[i][j][1] + bs);
          pk.z = f2b(acc[i][j][2] + bs);
          pk.w = f2b(acc[i][j][3] + bs);
          *reinterpret_cast<ushort4*>(vF + widx) = pk;
        }
      }
    }
  } else {
    #pragma unroll
    for (int j = 0; j < NJ; ++j){
      int o = ob + j*16 + lr;
      float bs = bias[o];
      #pragma unroll
      for (int i = 0; i < MI; ++i){
        int n0 = nb + i*16 + lg*4;
        f32x4 xr = *reinterpret_cast<const f32x4*>(xres + (size_t)o*NSP + n0);
        f32x4 ov;
        #pragma unroll
        for (int r = 0; r < 4; ++r) ov[r] = acc[i][j][r] + bs + xr[r];
        *reinterpret_cast<f32x4*>(outF + (size_t)o*NSP + n0) = ov;
      }
    }
  }
}

// ---------- flash attention v11: flash9 + 2 K-tiles per barrier (16 sync points) ----------
// Block = (head, b1, 64 q-rows), 8 waves = 2 qg x 4 kv-quarters. Stream kvh stages
// 8KB K-pairs (dbuf); V loaded to regs per tile (reg-dep synced, shadowed by compute).
// vmcnt(4) before barrier drains the K-pair stage (issued first, FIFO) while the
// next V quartet keeps flying.
__global__ __launch_bounds__(512) void flash11(
    const ushort* __restrict__ qS, const ushort* __restrict__ kF,
    const ushort* __restrict__ vF, ushort* __restrict__ attnT)
{
  __shared__ __align__(16) ushort ldsK[4][2][4096];   // [kvh][buf][8KB = 2 K tiles] = 64KB
  __shared__ __align__(16) float llds[3][64];
  __shared__ __align__(16) float winv[64];
  int lane = threadIdx.x & 63, wv = threadIdx.x >> 6;
  int l31 = lane & 31, hi = lane >> 5;
  int qg = wv & 1, kvh = wv >> 1;
  // bijective XCD swizzle: 512 blocks, 64/XCD -> one head per XCD
  int bx = (blockIdx.x & 7) * 64 + (blockIdx.x >> 3);
  int hh    = bx >> 6;
  int b1    = (bx >> 3) & 7;
  int chunk = bx & 7;
  int a0 = chunk * 64 + qg * 32;

  const ushort* qp = qS + ((size_t)((hh*8 + b1)*512) + a0 + l31)*64 + hi*8;
  s16x8 qf0 = ldfrag(qp), qf1 = ldfrag(qp+16), qf2 = ldfrag(qp+32), qf3 = ldfrag(qp+48);

  f32x16 O0 = {}, O1 = {};
  f32x4 lacc = {};
  s16x8 v0, v1, v2, v3;

  size_t tbase = (size_t)hh*262144 + (size_t)(kvh*32)*2048;

  // stream's 2 waves split an 8KB K-pair (wave-uniform LDS base + lane*16B: m104-safe)
  #define STAGEK2(BUF, PAIR) {                                                 \
    const ushort* ks_ = kF + tbase + (size_t)(PAIR)*4096 + qg*2048 + lane*8;   \
    ushort* lk_ = &ldsK[kvh][BUF][qg*2048 + lane*8];                           \
    gload16(ks_,        lk_);                                                  \
    gload16(ks_ +  512, lk_ +  512);                                           \
    gload16(ks_ + 1024, lk_ + 1024);                                           \
    gload16(ks_ + 1536, lk_ + 1536); }

  #define LOADV(T) {                                                           \
    const ushort* vp_ = vF + tbase + (size_t)(T)*2048 + lane*8;                \
    v0 = ldfrag(vp_);        v1 = ldfrag(vp_ + 512);                           \
    v2 = ldfrag(vp_ + 1024); v3 = ldfrag(vp_ + 1536); }

  #define COMPUTE(BUF, SLOT) {                                                 \
    const ushort* kc = &ldsK[kvh][BUF][(SLOT)*2048 + lane*8];                  \
    s16x8 k0 = *(const s16x8*)(kc),        k1 = *(const s16x8*)(kc +  512);    \
    s16x8 k2 = *(const s16x8*)(kc + 1024), k3 = *(const s16x8*)(kc + 1536);    \
    f32x16 S = {};                                                             \
    S = mfma32(k0, qf0, S); S = mfma32(k1, qf1, S);                            \
    S = mfma32(k2, qf2, S); S = mfma32(k3, qf3, S);                            \
    float p[16];                                                               \
    _Pragma("unroll") for (int r = 0; r < 16; ++r)                             \
      p[r] = __builtin_amdgcn_exp2f(S[r]);                                     \
    lacc[0] += (p[0]+p[1])   + (p[2]+p[3]);                                    \
    lacc[1] += (p[4]+p[5])   + (p[6]+p[7]);                                    \
    lacc[2] += (p[8]+p[9])   + (p[10]+p[11]);                                  \
    lacc[3] += (p[12]+p[13]) + (p[14]+p[15]);                                  \
    unsigned A0 = cvtpk(p[0],p[1]),  A1 = cvtpk(p[2],p[3]);                    \
    unsigned B0 = cvtpk(p[4],p[5]),  B1 = cvtpk(p[6],p[7]);                    \
    asm("v_permlane32_swap_b32 %0, %1" : "+v"(A0), "+v"(B0));                  \
    asm("v_permlane32_swap_b32 %0, %1" : "+v"(A1), "+v"(B1));                  \
    unsigned C0 = cvtpk(p[8],p[9]),  C1 = cvtpk(p[10],p[11]);                  \
    unsigned D0 = cvtpk(p[12],p[13]),D1 = cvtpk(p[14],p[15]);                  \
    asm("v_permlane32_swap_b32 %0, %1" : "+v"(C0), "+v"(D0));                  \
    asm("v_permlane32_swap_b32 %0, %1" : "+v"(C1), "+v"(D1));                  \
    u32x4 w1 = {A0, A1, B0, B1}, w2 = {C0, C1, D0, D1};                        \
    s16x8 pa1 = __builtin_bit_cast(s16x8, w1);                                 \
    s16x8 pa2 = __builtin_bit_cast(s16x8, w2);                                 \
    O0 = mfma32(pa1, v0, O0); O0 = mfma32(pa2, v1, O0);                        \
    O1 = mfma32(pa1, v2, O1); O1 = mfma32(pa2, v3, O1);                        \
  }

  STAGEK2(0, 0);
  __builtin_amdgcn_sched_barrier(0);
  LOADV(0);
  asm volatile("s_waitcnt vmcnt(4)" ::: "memory");
  __syncthreads();
  int cur = 0;
  for (int p2 = 0; p2 < 16; ++p2){
    if (p2 < 15){
      STAGEK2(cur^1, p2+1);
      __builtin_amdgcn_sched_barrier(0);
    }
    COMPUTE(cur, 0);          // PV uses V(2*p2); v-reg dep already satisfied
    LOADV(2*p2 + 1);
    COMPUTE(cur, 1);          // compiler waits V(2*p2+1) via reg dep
    if (p2 < 15){
      LOADV(2*p2 + 2);
      asm volatile("s_waitcnt vmcnt(4)" ::: "memory");  // drain K-pair; V quartet flies
    }
    __syncthreads();
    cur ^= 1;
  }
  #undef STAGEK2
  #undef LOADV
  #undef COMPUTE

  // per-stream l per q-row (valid in all lanes after swap)
  float ts = (lacc[0]+lacc[1]) + (lacc[2]+lacc[3]);
  float tu = ts, tv = ts;
  asm("v_permlane32_swap_b32 %0, %1" : "+v"(tu), "+v"(tv));
  float lrun = tu + tv;

  // ---- 4-way combine (plain sums): streams 0-2 park O as bf16 in their own dead
  // staging region (8KB); stream 3 merges. ----
  if (kvh < 3){
    ushort* park = &ldsK[kvh][0][0];
    #pragma unroll
    for (int g = 0; g < 4; ++g)
      #pragma unroll
      for (int r4 = 0; r4 < 4; ++r4){
        int fr = qg*32 + g*8 + hi*4 + r4;
        park[fr*64 + l31]      = f2b(O0[g*4+r4]);
        park[fr*64 + l31 + 32] = f2b(O1[g*4+r4]);
      }
    if (hi == 0) llds[kvh][qg*32 + l31] = lrun;
  }
  __syncthreads();
  if (kvh == 3){
    if (hi == 0){
      int idx = qg*32 + l31;
      winv[idx] = 1.0f / (llds[0][idx] + llds[1][idx] + llds[2][idx] + lrun);
    }
    asm volatile("s_waitcnt lgkmcnt(0)" ::: "memory");
    const ushort* p0 = &ldsK[0][0][0];
    const ushort* p1 = &ldsK[1][0][0];
    const ushort* p2 = &ldsK[2][0][0];
    size_t colBase = (size_t)b1*64 + l31;
    #pragma unroll
    for (int g = 0; g < 4; ++g){
      f32x4 iv = *reinterpret_cast<const f32x4*>(&winv[qg*32 + g*8 + hi*4]);
      #pragma unroll
      for (int r4 = 0; r4 < 4; ++r4){
        int row = g*8 + hi*4 + r4;
        int fr = qg*32 + row;
        float o0 = (b2f(p0[fr*64 + l31]) + b2f(p1[fr*64 + l31])
                  + b2f(p2[fr*64 + l31]) + O0[g*4+r4]) * iv[r4];
        float o1 = (b2f(p0[fr*64 + l31 + 32]) + b2f(p1[fr*64 + l31 + 32])
                  + b2f(p2[fr*64 + l31 + 32]) + O1[g*4+r4]) * iv[r4];
        size_t base = ((size_t)(hh*512 + a0 + row))*CHN + colBase;
        attnT[base]      = f2b(o0);
        attnT[base + 32] = f2b(o1);
      }
    }
  }
}

extern "C" void kernel_launch(void* const* d_in, const int* in_sizes, int n_in,
                              void* d_out, int out_size, void* d_ws, size_t ws_size,
                              hipStream_t stream)
{
  (void)in_sizes; (void)n_in; (void)out_size; (void)ws_size;
  const float* x     = (const float*)d_in[0];
  const float* normw = (const float*)d_in[1];
  const float* normb = (const float*)d_in[2];
  const float* qkvw  = (const float*)d_in[3];
  const float* qkvb  = (const float*)d_in[4];
  const float* projw = (const float*)d_in[5];
  const float* projb = (const float*)d_in[6];
  float* out = (float*)d_out;

  char* w = (char*)d_ws;
  ushort* h_t  = (ushort*)(w + 1024);                              // 4 MB ; aliased as attnT
  ushort* Wq   = (ushort*)(w + 1024 + 4194304);                    // 1.5 MB
  ushort* Wp   = (ushort*)(w + 1024 + 4194304 + 1572864);          // 0.5 MB
  ushort* qSb  = (ushort*)(w + 1024 + 4194304 + 1572864 + 524288); // 4 MB
  ushort* kFb  = qSb + 2097152;                                    // 4 MB (frag-major)
  ushort* vFb  = kFb + 2097152;                                    // 4 MB (frag-major)
  float*  part = (float*)(vFb + 2097152);                          // 2 KB (no alias)
  ushort* attnT = h_t;

  prep<<<1280, 256, 0, stream>>>((const float4*)qkvw, (const float4*)projw, x,
                                 (ushort4*)Wq, (ushort4*)Wp, part);
  norm_apply<<<512, 256, 0, stream>>>(x, part, normw, normb, h_t);
  gemm_tn<0,128,64><<<dim3(32, 24), 256, 0, stream>>>(h_t, Wq, qkvb, nullptr, qSb, kFb, vFb, nullptr);
  flash11<<<512, 512, 0, stream>>>(qSb, kFb, vFb, attnT);
  gemm_tn<1,64,64><<<dim3(64, 8), 256, 0, stream>>>(attnT, Wp, projb, x, nullptr, nullptr, nullptr, out);
}

// Round 15
// 86.029 us; speedup vs baseline: 1.0459x; 1.0459x over previous
//
#include <hip/hip_runtime.h>

typedef __attribute__((ext_vector_type(8)))  short s16x8;
typedef __attribute__((ext_vector_type(4)))  float f32x4;
typedef __attribute__((ext_vector_type(16))) float f32x16;
typedef __attribute__((ext_vector_type(4)))  unsigned int u32x4;

#define CHN 512
#define NSP 4096

__device__ __forceinline__ ushort f2b(float f){
  unsigned u = __builtin_bit_cast(unsigned, f);
  u = (u + 0x7fffu + ((u >> 16) & 1u)) >> 16;
  return (ushort)u;
}
__device__ __forceinline__ float b2f(ushort u){
  return __builtin_bit_cast(float, ((unsigned)u) << 16);
}

__device__ __forceinline__ s16x8 ldfrag(const void* p){
  return *reinterpret_cast<const s16x8*>(p);
}

__device__ __forceinline__ f32x4 mfma16(s16x8 a, s16x8 b, f32x4 c){
  return __builtin_amdgcn_mfma_f32_16x16x32_bf16(a, b, c, 0, 0, 0);
}
__device__ __forceinline__ f32x16 mfma32(s16x8 a, s16x8 b, f32x16 c){
  return __builtin_amdgcn_mfma_f32_32x32x16_bf16(a, b, c, 0, 0, 0);
}
__device__ __forceinline__ unsigned cvtpk(float lo, float hi){
  unsigned r;
  asm("v_cvt_pk_bf16_f32 %0, %1, %2" : "=v"(r) : "v"(lo), "v"(hi));
  return r;
}
__device__ __forceinline__ void gload16(const void* g, void* l){
  __builtin_amdgcn_global_load_lds(
      (const __attribute__((address_space(1))) unsigned int*)g,
      (__attribute__((address_space(3))) unsigned int*)l, 16, 0, 0);
}
__device__ __forceinline__ ushort4 f4b(float4 v){
  ushort4 o;
  o.x = f2b(v.x); o.y = f2b(v.y); o.z = f2b(v.z); o.w = f2b(v.w);
  return o;
}

// ---------- fused preprocessing: weight cvt (qkv, proj) + group-norm partials ----------
__global__ __launch_bounds__(256) void prep(const float4* __restrict__ qkvw, const float4* __restrict__ projw,
                                            const float* __restrict__ x,
                                            ushort4* __restrict__ Wq, ushort4* __restrict__ Wp,
                                            float* __restrict__ part){
  int b = blockIdx.x;
  if (b < 768){
    int i = b*256 + threadIdx.x;
    Wq[i] = f4b(qkvw[i]);
  } else if (b < 1024){
    int i = (b-768)*256 + threadIdx.x;
    Wp[i] = f4b(projw[i]);
  } else {
    int pb = b - 1024;
    const float4* p = reinterpret_cast<const float4*>(x + (size_t)pb * 8192);
    float s = 0.f, s2 = 0.f;
    #pragma unroll
    for (int i = 0; i < 8; ++i){
      float4 v = p[threadIdx.x + i*256];
      s  += v.x + v.y + v.z + v.w;
      s2 += v.x*v.x + v.y*v.y + v.z*v.z + v.w*v.w;
    }
    #pragma unroll
    for (int off = 32; off > 0; off >>= 1){ s += __shfl_down(s, off); s2 += __shfl_down(s2, off); }
    __shared__ float ls[4], ls2[4];
    int wv = threadIdx.x >> 6;
    if ((threadIdx.x & 63) == 0){ ls[wv] = s; ls2[wv] = s2; }
    __syncthreads();
    if (threadIdx.x == 0){
      part[pb*2]     = ls[0]+ls[1]+ls[2]+ls[3];
      part[pb*2 + 1] = ls2[0]+ls2[1]+ls2[2]+ls2[3];
    }
  }
}

// ---------- fused gn-final + norm + SiLU + transpose: x (C,N) fp32 -> h_t (N,C) bf16 ----------
__global__ __launch_bounds__(256) void norm_apply(const float* __restrict__ x, const float* __restrict__ part,
                                                  const float* __restrict__ nw, const float* __restrict__ nb,
                                                  ushort* __restrict__ h_t){
  __shared__ float tile[64][65];
  __shared__ float smu[32], srs[32];
  if (threadIdx.x < 32){
    int g = threadIdx.x;
    float s = 0.f, s2 = 0.f;
    #pragma unroll
    for (int i = 0; i < 8; ++i){ s += part[(g*8+i)*2]; s2 += part[(g*8+i)*2+1]; }
    float mu  = s * (1.f/65536.f);
    float var = s2 * (1.f/65536.f) - mu*mu;
    smu[g] = mu;
    srs[g] = rsqrtf(var + 1e-5f);
  }
  __syncthreads();
  int ct0 = (blockIdx.x >> 6) << 6;
  int nt0 = (blockIdx.x & 63) << 6;
  int tc = threadIdx.x >> 6;
  int tn = threadIdx.x & 63;
  #pragma unroll
  for (int rr = 0; rr < 16; ++rr){
    int cl = rr*4 + tc;
    int c  = ct0 + cl;
    float v  = x[(size_t)c * NSP + nt0 + tn];
    float hn = (v - smu[c >> 4]) * srs[c >> 4] * nw[c] + nb[c];
    float sv = hn / (1.f + __expf(-hn));
    tile[tn][cl] = sv;
  }
  __syncthreads();
  #pragma unroll
  for (int rr = 0; rr < 16; ++rr){
    int nl = rr*4 + tc;
    h_t[(size_t)(nt0 + nl) * CHN + ct0 + tn] = f2b(tile[nl][tn]);
  }
}

// ---------- GEMM: C(n,o) = A(n,c) * Bw(o,c)^T, LDS-staged 2-phase ----------
template<int MODE, int BM, int BN>
__global__ __launch_bounds__(256) void gemm_tn(
    const ushort* __restrict__ A, const ushort* __restrict__ Bw,
    const float* __restrict__ bias, const float* __restrict__ xres,
    ushort* __restrict__ qS, ushort* __restrict__ kF, ushort* __restrict__ vF,
    float* __restrict__ outF)
{
  constexpr int RW = BM/2, CW = BN/2;
  constexpr int MI = RW/16, NJ = CW/16;
  __shared__ __align__(16) ushort As[2][BM*32];
  __shared__ __align__(16) ushort Bs[2][BN*32];
  int tid = threadIdx.x;
  int lane = tid & 63, wv = tid >> 6;
  int lr = lane & 15, lg = lane >> 4;
  int wr = wv >> 1, wc = wv & 1;
  int nbB = blockIdx.x * BM;
  int obB = blockIdx.y * BN;
  int nb = nbB + wr*RW, ob = obB + wc*CW;
  f32x4 acc[MI][NJ] = {};

  const ushort* Ag = A  + (size_t)(nbB + (tid>>2))*CHN + (tid&3)*8;
  const ushort* Bg = Bw + (size_t)(obB + (tid>>2))*CHN + (tid&3)*8;

  #define GSTAGE(BUF, KK) {                                                    \
    _Pragma("unroll") for (int ii = 0; ii < BM/64; ++ii)                       \
      gload16(Ag + (size_t)ii*64*CHN + (KK), &As[BUF][ii*2048 + tid*8]);       \
    _Pragma("unroll") for (int ii = 0; ii < BN/64; ++ii)                       \
      gload16(Bg + (size_t)ii*64*CHN + (KK), &Bs[BUF][ii*2048 + tid*8]); }

  GSTAGE(0, 0);
  asm volatile("s_waitcnt vmcnt(0)" ::: "memory");
  __syncthreads();
  int cur = 0;
  for (int kk = 0; kk < CHN; kk += 32){
    if (kk < CHN-32) GSTAGE(cur^1, kk+32);
    s16x8 af[MI], bf[NJ];
    #pragma unroll
    for (int t = 0; t < MI; ++t) af[t] = *(const s16x8*)&As[cur][(wr*RW + lr + t*16)*32 + lg*8];
    #pragma unroll
    for (int t = 0; t < NJ; ++t) bf[t] = *(const s16x8*)&Bs[cur][(wc*CW + lr + t*16)*32 + lg*8];
    #pragma unroll
    for (int i = 0; i < MI; ++i)
      #pragma unroll
      for (int j = 0; j < NJ; ++j)
        acc[i][j] = mfma16(af[i], bf[j], acc[i][j]);
    asm volatile("s_waitcnt vmcnt(0)" ::: "memory");
    __syncthreads();
    cur ^= 1;
  }
  #undef GSTAGE

  if (MODE == 0){
    #pragma unroll
    for (int j = 0; j < NJ; ++j){
      int o = ob + j*16 + lr;
      float bs = bias[o];
      int sec = o >> 9;        // 0=Q 1=K 2=V  (uniform per wave)
      int co  = o & 511;
      int bb = co >> 6, dd = co & 63;
      if (sec == 0){
        const float qsc = 0.18033688011112042f;  // 0.125*log2(e)
        #pragma unroll
        for (int i = 0; i < MI; ++i){
          int n0 = nb + i*16 + lg*4;
          int hh = n0 >> 9, aa = n0 & 511;
          size_t base = ((size_t)((hh<<3)+bb)*512 + aa)*64 + dd;
          #pragma unroll
          for (int r = 0; r < 4; ++r)
            qS[base + (size_t)r*64] = f2b((acc[i][j][r] + bs) * qsc);
        }
      } else if (sec == 1){
        int s = dd >> 4, khi = (dd >> 3) & 1, off = dd & 7;
        #pragma unroll
        for (int i = 0; i < MI; ++i){
          int n0 = nb + i*16 + lg*4;
          int hh = n0 >> 9, aa = n0 & 511;
          int T = bb*16 + (aa >> 5);
          size_t widx = ((((size_t)hh*128 + T)*4 + s)*64 + (aa & 31) + 32*khi)*8 + off;
          #pragma unroll
          for (int r = 0; r < 4; ++r)
            kF[widx + (size_t)r*8] = f2b(acc[i][j][r] + bs);
        }
      } else {
        int l31v = dd & 31, fh = dd >> 5;
        #pragma unroll
        for (int i = 0; i < MI; ++i){
          int n0 = nb + i*16 + lg*4;
          int hh = n0 >> 9, aa = n0 & 511;
          int T = bb*16 + (aa >> 5);
          int w = aa & 31;
          int f = fh*2 + (w >> 4);
          int vhi = (w >> 3) & 1, koff = w & 7;
          size_t widx = ((((size_t)hh*128 + T)*4 + f)*64 + l31v + 32*vhi)*8 + koff;
          ushort4 pk;
          pk.x = f2b(acc[i][j][0] + bs);
          pk.y = f2b(acc[i][j][1] + bs);
          pk.z = f2b(acc[i][j][2] + bs);
          pk.w = f2b(acc[i][j][3] + bs);
          *reinterpret_cast<ushort4*>(vF + widx) = pk;
        }
      }
    }
  } else {
    #pragma unroll
    for (int j = 0; j < NJ; ++j){
      int o = ob + j*16 + lr;
      float bs = bias[o];
      #pragma unroll
      for (int i = 0; i < MI; ++i){
        int n0 = nb + i*16 + lg*4;
        f32x4 xr = *reinterpret_cast<const f32x4*>(xres + (size_t)o*NSP + n0);
        f32x4 ov;
        #pragma unroll
        for (int r = 0; r < 4; ++r) ov[r] = acc[i][j][r] + bs + xr[r];
        *reinterpret_cast<f32x4*>(outF + (size_t)o*NSP + n0) = ov;
      }
    }
  }
}

// ---------- flash attention v9 + T5 setprio (verified 48.6-48.9us base) ----------
// Block = (head, b1, 64 q-rows), 8 waves = 2 qg x 4 kv-quarters. Stream kvh stages only K
// (4KB tiles, dbuf); V loaded to regs after PV(t) (shadowed by next tile's QK+softmax).
// Barrier drain is vmcnt(4): K gloads (issued first, FIFO) proven done, V loads keep flying.
// T5: setprio(1) around the MFMA cluster -- streams are decoupled between barriers,
// so wave role-diversity exists (staging vs softmax vs MFMA) and priority can arbitrate.
__global__ __launch_bounds__(512) void flash9(
    const ushort* __restrict__ qS, const ushort* __restrict__ kF,
    const ushort* __restrict__ vF, ushort* __restrict__ attnT)
{
  __shared__ __align__(16) ushort ldsK[4][2][2048];   // [kvh][buf][4KB K tile] = 32KB
  __shared__ __align__(16) float llds[3][64];
  __shared__ __align__(16) float winv[64];
  int lane = threadIdx.x & 63, wv = threadIdx.x >> 6;
  int l31 = lane & 31, hi = lane >> 5;
  int qg = wv & 1, kvh = wv >> 1;
  // bijective XCD swizzle: 512 blocks, 64/XCD -> one head per XCD
  int bx = (blockIdx.x & 7) * 64 + (blockIdx.x >> 3);
  int hh    = bx >> 6;
  int b1    = (bx >> 3) & 7;
  int chunk = bx & 7;
  int a0 = chunk * 64 + qg * 32;

  const ushort* qp = qS + ((size_t)((hh*8 + b1)*512) + a0 + l31)*64 + hi*8;
  s16x8 qf0 = ldfrag(qp), qf1 = ldfrag(qp+16), qf2 = ldfrag(qp+32), qf3 = ldfrag(qp+48);

  f32x16 O0 = {}, O1 = {};
  f32x4 lacc = {};
  s16x8 v0, v1, v2, v3;

  size_t tbase = (size_t)hh*262144 + (size_t)(kvh*32)*2048;

  // stream's 2 waves split the 4KB K tile (wave-uniform LDS base + lane*16B: m104-safe)
  #define STAGEK(BUF, T) {                                                     \
    const ushort* ks_ = kF + tbase + (size_t)(T)*2048 + qg*1024 + lane*8;      \
    ushort* lk_ = &ldsK[kvh][BUF][qg*1024 + lane*8];                           \
    gload16(ks_,       lk_);                                                   \
    gload16(ks_ + 512, lk_ + 512); }

  #define LOADV(T) {                                                           \
    const ushort* vp_ = vF + tbase + (size_t)(T)*2048 + lane*8;                \
    v0 = ldfrag(vp_);        v1 = ldfrag(vp_ + 512);                           \
    v2 = ldfrag(vp_ + 1024); v3 = ldfrag(vp_ + 1536); }

  #define COMPUTE(BUF) {                                                       \
    const ushort* kc = &ldsK[kvh][BUF][lane*8];                                \
    s16x8 k0 = *(const s16x8*)(kc),        k1 = *(const s16x8*)(kc +  512);    \
    s16x8 k2 = *(const s16x8*)(kc + 1024), k3 = *(const s16x8*)(kc + 1536);    \
    f32x16 S = {};                                                             \
    __builtin_amdgcn_s_setprio(1);                                             \
    S = mfma32(k0, qf0, S); S = mfma32(k1, qf1, S);                            \
    S = mfma32(k2, qf2, S); S = mfma32(k3, qf3, S);                            \
    __builtin_amdgcn_s_setprio(0);                                             \
    float p[16];                                                               \
    _Pragma("unroll") for (int r = 0; r < 16; ++r)                             \
      p[r] = __builtin_amdgcn_exp2f(S[r]);                                     \
    lacc[0] += (p[0]+p[1])   + (p[2]+p[3]);                                    \
    lacc[1] += (p[4]+p[5])   + (p[6]+p[7]);                                    \
    lacc[2] += (p[8]+p[9])   + (p[10]+p[11]);                                  \
    lacc[3] += (p[12]+p[13]) + (p[14]+p[15]);                                  \
    unsigned A0 = cvtpk(p[0],p[1]),  A1 = cvtpk(p[2],p[3]);                    \
    unsigned B0 = cvtpk(p[4],p[5]),  B1 = cvtpk(p[6],p[7]);                    \
    asm("v_permlane32_swap_b32 %0, %1" : "+v"(A0), "+v"(B0));                  \
    asm("v_permlane32_swap_b32 %0, %1" : "+v"(A1), "+v"(B1));                  \
    unsigned C0 = cvtpk(p[8],p[9]),  C1 = cvtpk(p[10],p[11]);                  \
    unsigned D0 = cvtpk(p[12],p[13]),D1 = cvtpk(p[14],p[15]);                  \
    asm("v_permlane32_swap_b32 %0, %1" : "+v"(C0), "+v"(D0));                  \
    asm("v_permlane32_swap_b32 %0, %1" : "+v"(C1), "+v"(D1));                  \
    u32x4 w1 = {A0, A1, B0, B1}, w2 = {C0, C1, D0, D1};                        \
    s16x8 pa1 = __builtin_bit_cast(s16x8, w1);                                 \
    s16x8 pa2 = __builtin_bit_cast(s16x8, w2);                                 \
    __builtin_amdgcn_s_setprio(1);                                             \
    O0 = mfma32(pa1, v0, O0); O0 = mfma32(pa2, v1, O0);                        \
    O1 = mfma32(pa1, v2, O1); O1 = mfma32(pa2, v3, O1);                        \
    __builtin_amdgcn_s_setprio(0);                                             \
  }

  STAGEK(0, 0);
  __builtin_amdgcn_sched_barrier(0);
  LOADV(0);
  asm volatile("s_waitcnt vmcnt(4)" ::: "memory");
  __syncthreads();
  int cur = 0;
  for (int t = 0; t < 32; ++t){
    if (t < 31){
      STAGEK(cur^1, t+1);
      __builtin_amdgcn_sched_barrier(0);
    }
    COMPUTE(cur);
    if (t < 31){
      LOADV(t+1);
      asm volatile("s_waitcnt vmcnt(4)" ::: "memory");
    }
    __syncthreads();
    cur ^= 1;
  }
  #undef STAGEK
  #undef LOADV
  #undef COMPUTE

  // per-stream l per q-row (valid in all lanes after swap)
  float ts = (lacc[0]+lacc[1]) + (lacc[2]+lacc[3]);
  float tu = ts, tv = ts;
  asm("v_permlane32_swap_b32 %0, %1" : "+v"(tu), "+v"(tv));
  float lrun = tu + tv;

  // ---- 4-way combine (plain sums): streams 0-2 park O as bf16 in their own dead
  // staging region (8KB = 64 rows x 64 cols); stream 3 merges. ----
  if (kvh < 3){
    ushort* park = &ldsK[kvh][0][0];
    #pragma unroll
    for (int g = 0; g < 4; ++g)
      #pragma unroll
      for (int r4 = 0; r4 < 4; ++r4){
        int fr = qg*32 + g*8 + hi*4 + r4;
        park[fr*64 + l31]      = f2b(O0[g*4+r4]);
        park[fr*64 + l31 + 32] = f2b(O1[g*4+r4]);
      }
    if (hi == 0) llds[kvh][qg*32 + l31] = lrun;
  }
  __syncthreads();
  if (kvh == 3){
    if (hi == 0){
      int idx = qg*32 + l31;
      winv[idx] = 1.0f / (llds[0][idx] + llds[1][idx] + llds[2][idx] + lrun);
    }
    asm volatile("s_waitcnt lgkmcnt(0)" ::: "memory");
    const ushort* p0 = &ldsK[0][0][0];
    const ushort* p1 = &ldsK[1][0][0];
    const ushort* p2 = &ldsK[2][0][0];
    size_t colBase = (size_t)b1*64 + l31;
    #pragma unroll
    for (int g = 0; g < 4; ++g){
      f32x4 iv = *reinterpret_cast<const f32x4*>(&winv[qg*32 + g*8 + hi*4]);
      #pragma unroll
      for (int r4 = 0; r4 < 4; ++r4){
        int row = g*8 + hi*4 + r4;
        int fr = qg*32 + row;
        float o0 = (b2f(p0[fr*64 + l31]) + b2f(p1[fr*64 + l31])
                  + b2f(p2[fr*64 + l31]) + O0[g*4+r4]) * iv[r4];
        float o1 = (b2f(p0[fr*64 + l31 + 32]) + b2f(p1[fr*64 + l31 + 32])
                  + b2f(p2[fr*64 + l31 + 32]) + O1[g*4+r4]) * iv[r4];
        size_t base = ((size_t)(hh*512 + a0 + row))*CHN + colBase;
        attnT[base]      = f2b(o0);
        attnT[base + 32] = f2b(o1);
      }
    }
  }
}

extern "C" void kernel_launch(void* const* d_in, const int* in_sizes, int n_in,
                              void* d_out, int out_size, void* d_ws, size_t ws_size,
                              hipStream_t stream)
{
  (void)in_sizes; (void)n_in; (void)out_size; (void)ws_size;
  const float* x     = (const float*)d_in[0];
  const float* normw = (const float*)d_in[1];
  const float* normb = (const float*)d_in[2];
  const float* qkvw  = (const float*)d_in[3];
  const float* qkvb  = (const float*)d_in[4];
  const float* projw = (const float*)d_in[5];
  const float* projb = (const float*)d_in[6];
  float* out = (float*)d_out;

  char* w = (char*)d_ws;
  ushort* h_t  = (ushort*)(w + 1024);                              // 4 MB ; aliased as attnT
  ushort* Wq   = (ushort*)(w + 1024 + 4194304);                    // 1.5 MB
  ushort* Wp   = (ushort*)(w + 1024 + 4194304 + 1572864);          // 0.5 MB
  ushort* qSb  = (ushort*)(w + 1024 + 4194304 + 1572864 + 524288); // 4 MB
  ushort* kFb  = qSb + 2097152;                                    // 4 MB (frag-major)
  ushort* vFb  = kFb + 2097152;                                    // 4 MB (frag-major)
  float*  part = (float*)(vFb + 2097152);                          // 2 KB (no alias)
  ushort* attnT = h_t;

  prep<<<1280, 256, 0, stream>>>((const float4*)qkvw, (const float4*)projw, x,
                                 (ushort4*)Wq, (ushort4*)Wp, part);
  norm_apply<<<512, 256, 0, stream>>>(x, part, normw, normb, h_t);
  gemm_tn<0,128,64><<<dim3(32, 24), 256, 0, stream>>>(h_t, Wq, qkvb, nullptr, qSb, kFb, vFb, nullptr);
  flash9<<<512, 512, 0, stream>>>(qSb, kFb, vFb, attnT);
  gemm_tn<1,64,64><<<dim3(64, 8), 256, 0, stream>>>(attnT, Wp, projb, x, nullptr, nullptr, nullptr, out);
}

// Round 16
// 84.132 us; speedup vs baseline: 1.0695x; 1.0225x over previous
//
#include <hip/hip_runtime.h>

typedef __attribute__((ext_vector_type(8)))  short s16x8;
typedef __attribute__((ext_vector_type(4)))  float f32x4;
typedef __attribute__((ext_vector_type(16))) float f32x16;
typedef __attribute__((ext_vector_type(4)))  unsigned int u32x4;

#define CHN 512
#define NSP 4096

__device__ __forceinline__ ushort f2b(float f){
  unsigned u = __builtin_bit_cast(unsigned, f);
  u = (u + 0x7fffu + ((u >> 16) & 1u)) >> 16;
  return (ushort)u;
}
__device__ __forceinline__ float b2f(ushort u){
  return __builtin_bit_cast(float, ((unsigned)u) << 16);
}

__device__ __forceinline__ s16x8 ldfrag(const void* p){
  return *reinterpret_cast<const s16x8*>(p);
}

__device__ __forceinline__ f32x4 mfma16(s16x8 a, s16x8 b, f32x4 c){
  return __builtin_amdgcn_mfma_f32_16x16x32_bf16(a, b, c, 0, 0, 0);
}
__device__ __forceinline__ f32x16 mfma32(s16x8 a, s16x8 b, f32x16 c){
  return __builtin_amdgcn_mfma_f32_32x32x16_bf16(a, b, c, 0, 0, 0);
}
__device__ __forceinline__ unsigned cvtpk(float lo, float hi){
  unsigned r;
  asm("v_cvt_pk_bf16_f32 %0, %1, %2" : "=v"(r) : "v"(lo), "v"(hi));
  return r;
}
__device__ __forceinline__ void gload16(const void* g, void* l){
  __builtin_amdgcn_global_load_lds(
      (const __attribute__((address_space(1))) unsigned int*)g,
      (__attribute__((address_space(3))) unsigned int*)l, 16, 0, 0);
}
__device__ __forceinline__ ushort4 f4b(float4 v){
  ushort4 o;
  o.x = f2b(v.x); o.y = f2b(v.y); o.z = f2b(v.z); o.w = f2b(v.w);
  return o;
}

// ---------- fused preprocessing: weight cvt (qkv, proj) + group-norm partials ----------
__global__ __launch_bounds__(256) void prep(const float4* __restrict__ qkvw, const float4* __restrict__ projw,
                                            const float* __restrict__ x,
                                            ushort4* __restrict__ Wq, ushort4* __restrict__ Wp,
                                            float* __restrict__ part){
  int b = blockIdx.x;
  if (b < 768){
    int i = b*256 + threadIdx.x;
    Wq[i] = f4b(qkvw[i]);
  } else if (b < 1024){
    int i = (b-768)*256 + threadIdx.x;
    Wp[i] = f4b(projw[i]);
  } else {
    int pb = b - 1024;
    const float4* p = reinterpret_cast<const float4*>(x + (size_t)pb * 8192);
    float s = 0.f, s2 = 0.f;
    #pragma unroll
    for (int i = 0; i < 8; ++i){
      float4 v = p[threadIdx.x + i*256];
      s  += v.x + v.y + v.z + v.w;
      s2 += v.x*v.x + v.y*v.y + v.z*v.z + v.w*v.w;
    }
    #pragma unroll
    for (int off = 32; off > 0; off >>= 1){ s += __shfl_down(s, off); s2 += __shfl_down(s2, off); }
    __shared__ float ls[4], ls2[4];
    int wv = threadIdx.x >> 6;
    if ((threadIdx.x & 63) == 0){ ls[wv] = s; ls2[wv] = s2; }
    __syncthreads();
    if (threadIdx.x == 0){
      part[pb*2]     = ls[0]+ls[1]+ls[2]+ls[3];
      part[pb*2 + 1] = ls2[0]+ls2[1]+ls2[2]+ls2[3];
    }
  }
}

// ---------- fused gn-final + norm + SiLU + transpose: x (C,N) fp32 -> h_t (N,C) bf16 ----------
__global__ __launch_bounds__(256) void norm_apply(const float* __restrict__ x, const float* __restrict__ part,
                                                  const float* __restrict__ nw, const float* __restrict__ nb,
                                                  ushort* __restrict__ h_t){
  __shared__ float tile[64][65];
  __shared__ float smu[32], srs[32];
  if (threadIdx.x < 32){
    int g = threadIdx.x;
    float s = 0.f, s2 = 0.f;
    #pragma unroll
    for (int i = 0; i < 8; ++i){ s += part[(g*8+i)*2]; s2 += part[(g*8+i)*2+1]; }
    float mu  = s * (1.f/65536.f);
    float var = s2 * (1.f/65536.f) - mu*mu;
    smu[g] = mu;
    srs[g] = rsqrtf(var + 1e-5f);
  }
  __syncthreads();
  int ct0 = (blockIdx.x >> 6) << 6;
  int nt0 = (blockIdx.x & 63) << 6;
  int tc = threadIdx.x >> 6;
  int tn = threadIdx.x & 63;
  #pragma unroll
  for (int rr = 0; rr < 16; ++rr){
    int cl = rr*4 + tc;
    int c  = ct0 + cl;
    float v  = x[(size_t)c * NSP + nt0 + tn];
    float hn = (v - smu[c >> 4]) * srs[c >> 4] * nw[c] + nb[c];
    float sv = hn / (1.f + __expf(-hn));
    tile[tn][cl] = sv;
  }
  __syncthreads();
  #pragma unroll
  for (int rr = 0; rr < 16; ++rr){
    int nl = rr*4 + tc;
    h_t[(size_t)(nt0 + nl) * CHN + ct0 + tn] = f2b(tile[nl][tn]);
  }
}

// ---------- GEMM: C(n,o) = A(n,c) * Bw(o,c)^T, LDS-staged 2-phase ----------
// T2 bank-conflict fix (rule #21 both-sides): LDS dest stays LINEAR (gload16
// requirement); the 16B slot within each 64B row is XOR-swizzled on the GLOBAL
// source (slot ^= row&3) and the same XOR is applied on the ds_read address.
// 8-way -> 4-way aliasing on fragment reads.
template<int MODE, int BM, int BN>
__global__ __launch_bounds__(256) void gemm_tn(
    const ushort* __restrict__ A, const ushort* __restrict__ Bw,
    const float* __restrict__ bias, const float* __restrict__ xres,
    ushort* __restrict__ qS, ushort* __restrict__ kF, ushort* __restrict__ vF,
    float* __restrict__ outF)
{
  constexpr int RW = BM/2, CW = BN/2;
  constexpr int MI = RW/16, NJ = CW/16;
  __shared__ __align__(16) ushort As[2][BM*32];
  __shared__ __align__(16) ushort Bs[2][BN*32];
  int tid = threadIdx.x;
  int lane = tid & 63, wv = tid >> 6;
  int lr = lane & 15, lg = lane >> 4;
  int wr = wv >> 1, wc = wv & 1;
  int nbB = blockIdx.x * BM;
  int obB = blockIdx.y * BN;
  int nb = nbB + wr*RW, ob = obB + wc*CW;
  f32x4 acc[MI][NJ] = {};

  // staging: row = ii*64 + (tid>>2), slot = tid&3; source slot pre-swizzled by row&3
  int sswz = (tid & 3) ^ ((tid >> 2) & 3);
  const ushort* Ag = A  + (size_t)(nbB + (tid>>2))*CHN + sswz*8;
  const ushort* Bg = Bw + (size_t)(obB + (tid>>2))*CHN + sswz*8;
  int rdswz = (lg ^ (lr & 3)) * 8;

  #define GSTAGE(BUF, KK) {                                                    \
    _Pragma("unroll") for (int ii = 0; ii < BM/64; ++ii)                       \
      gload16(Ag + (size_t)ii*64*CHN + (KK), &As[BUF][ii*2048 + tid*8]);       \
    _Pragma("unroll") for (int ii = 0; ii < BN/64; ++ii)                       \
      gload16(Bg + (size_t)ii*64*CHN + (KK), &Bs[BUF][ii*2048 + tid*8]); }

  GSTAGE(0, 0);
  asm volatile("s_waitcnt vmcnt(0)" ::: "memory");
  __syncthreads();
  int cur = 0;
  for (int kk = 0; kk < CHN; kk += 32){
    if (kk < CHN-32) GSTAGE(cur^1, kk+32);
    s16x8 af[MI], bf[NJ];
    #pragma unroll
    for (int t = 0; t < MI; ++t) af[t] = *(const s16x8*)&As[cur][(wr*RW + lr + t*16)*32 + rdswz];
    #pragma unroll
    for (int t = 0; t < NJ; ++t) bf[t] = *(const s16x8*)&Bs[cur][(wc*CW + lr + t*16)*32 + rdswz];
    #pragma unroll
    for (int i = 0; i < MI; ++i)
      #pragma unroll
      for (int j = 0; j < NJ; ++j)
        acc[i][j] = mfma16(af[i], bf[j], acc[i][j]);
    asm volatile("s_waitcnt vmcnt(0)" ::: "memory");
    __syncthreads();
    cur ^= 1;
  }
  #undef GSTAGE

  if (MODE == 0){
    #pragma unroll
    for (int j = 0; j < NJ; ++j){
      int o = ob + j*16 + lr;
      float bs = bias[o];
      int sec = o >> 9;        // 0=Q 1=K 2=V  (uniform per wave)
      int co  = o & 511;
      int bb = co >> 6, dd = co & 63;
      if (sec == 0){
        const float qsc = 0.18033688011112042f;  // 0.125*log2(e)
        #pragma unroll
        for (int i = 0; i < MI; ++i){
          int n0 = nb + i*16 + lg*4;
          int hh = n0 >> 9, aa = n0 & 511;
          size_t base = ((size_t)((hh<<3)+bb)*512 + aa)*64 + dd;
          #pragma unroll
          for (int r = 0; r < 4; ++r)
            qS[base + (size_t)r*64] = f2b((acc[i][j][r] + bs) * qsc);
        }
      } else if (sec == 1){
        int s = dd >> 4, khi = (dd >> 3) & 1, off = dd & 7;
        #pragma unroll
        for (int i = 0; i < MI; ++i){
          int n0 = nb + i*16 + lg*4;
          int hh = n0 >> 9, aa = n0 & 511;
          int T = bb*16 + (aa >> 5);
          size_t widx = ((((size_t)hh*128 + T)*4 + s)*64 + (aa & 31) + 32*khi)*8 + off;
          #pragma unroll
          for (int r = 0; r < 4; ++r)
            kF[widx + (size_t)r*8] = f2b(acc[i][j][r] + bs);
        }
      } else {
        int l31v = dd & 31, fh = dd >> 5;
        #pragma unroll
        for (int i = 0; i < MI; ++i){
          int n0 = nb + i*16 + lg*4;
          int hh = n0 >> 9, aa = n0 & 511;
          int T = bb*16 + (aa >> 5);
          int w = aa & 31;
          int f = fh*2 + (w >> 4);
          int vhi = (w >> 3) & 1, koff = w & 7;
          size_t widx = ((((size_t)hh*128 + T)*4 + f)*64 + l31v + 32*vhi)*8 + koff;
          ushort4 pk;
          pk.x = f2b(acc[i][j][0] + bs);
          pk.y = f2b(acc[i][j][1] + bs);
          pk.z = f2b(acc[i][j][2] + bs);
          pk.w = f2b(acc[i][j][3] + bs);
          *reinterpret_cast<ushort4*>(vF + widx) = pk;
        }
      }
    }
  } else {
    #pragma unroll
    for (int j = 0; j < NJ; ++j){
      int o = ob + j*16 + lr;
      float bs = bias[o];
      #pragma unroll
      for (int i = 0; i < MI; ++i){
        int n0 = nb + i*16 + lg*4;
        f32x4 xr = *reinterpret_cast<const f32x4*>(xres + (size_t)o*NSP + n0);
        f32x4 ov;
        #pragma unroll
        for (int r = 0; r < 4; ++r) ov[r] = acc[i][j][r] + bs + xr[r];
        *reinterpret_cast<f32x4*>(outF + (size_t)o*NSP + n0) = ov;
      }
    }
  }
}

// ---------- flash attention v9 (verified 48.6-48.9us): V direct-to-reg, K-only LDS, counted vmcnt ----------
// Block = (head, b1, 64 q-rows), 8 waves = 2 qg x 4 kv-quarters. Stream kvh stages only K
// (4KB tiles, dbuf); V loaded to regs after PV(t) (shadowed by next tile's QK+softmax).
// Barrier drain is vmcnt(4): K gloads (issued first, FIFO) proven done, V loads keep flying.
__global__ __launch_bounds__(512) void flash9(
    const ushort* __restrict__ qS, const ushort* __restrict__ kF,
    const ushort* __restrict__ vF, ushort* __restrict__ attnT)
{
  __shared__ __align__(16) ushort ldsK[4][2][2048];   // [kvh][buf][4KB K tile] = 32KB
  __shared__ __align__(16) float llds[3][64];
  __shared__ __align__(16) float winv[64];
  int lane = threadIdx.x & 63, wv = threadIdx.x >> 6;
  int l31 = lane & 31, hi = lane >> 5;
  int qg = wv & 1, kvh = wv >> 1;
  // bijective XCD swizzle: 512 blocks, 64/XCD -> one head per XCD
  int bx = (blockIdx.x & 7) * 64 + (blockIdx.x >> 3);
  int hh    = bx >> 6;
  int b1    = (bx >> 3) & 7;
  int chunk = bx & 7;
  int a0 = chunk * 64 + qg * 32;

  const ushort* qp = qS + ((size_t)((hh*8 + b1)*512) + a0 + l31)*64 + hi*8;
  s16x8 qf0 = ldfrag(qp), qf1 = ldfrag(qp+16), qf2 = ldfrag(qp+32), qf3 = ldfrag(qp+48);

  f32x16 O0 = {}, O1 = {};
  f32x4 lacc = {};
  s16x8 v0, v1, v2, v3;

  size_t tbase = (size_t)hh*262144 + (size_t)(kvh*32)*2048;

  // stream's 2 waves split the 4KB K tile (wave-uniform LDS base + lane*16B: m104-safe)
  #define STAGEK(BUF, T) {                                                     \
    const ushort* ks_ = kF + tbase + (size_t)(T)*2048 + qg*1024 + lane*8;      \
    ushort* lk_ = &ldsK[kvh][BUF][qg*1024 + lane*8];                           \
    gload16(ks_,       lk_);                                                   \
    gload16(ks_ + 512, lk_ + 512); }

  #define LOADV(T) {                                                           \
    const ushort* vp_ = vF + tbase + (size_t)(T)*2048 + lane*8;                \
    v0 = ldfrag(vp_);        v1 = ldfrag(vp_ + 512);                           \
    v2 = ldfrag(vp_ + 1024); v3 = ldfrag(vp_ + 1536); }

  #define COMPUTE(BUF) {                                                       \
    const ushort* kc = &ldsK[kvh][BUF][lane*8];                                \
    s16x8 k0 = *(const s16x8*)(kc),        k1 = *(const s16x8*)(kc +  512);    \
    s16x8 k2 = *(const s16x8*)(kc + 1024), k3 = *(const s16x8*)(kc + 1536);    \
    f32x16 S = {};                                                             \
    S = mfma32(k0, qf0, S); S = mfma32(k1, qf1, S);                            \
    S = mfma32(k2, qf2, S); S = mfma32(k3, qf3, S);                            \
    float p[16];                                                               \
    _Pragma("unroll") for (int r = 0; r < 16; ++r)                             \
      p[r] = __builtin_amdgcn_exp2f(S[r]);                                     \
    lacc[0] += (p[0]+p[1])   + (p[2]+p[3]);                                    \
    lacc[1] += (p[4]+p[5])   + (p[6]+p[7]);                                    \
    lacc[2] += (p[8]+p[9])   + (p[10]+p[11]);                                  \
    lacc[3] += (p[12]+p[13]) + (p[14]+p[15]);                                  \
    unsigned A0 = cvtpk(p[0],p[1]),  A1 = cvtpk(p[2],p[3]);                    \
    unsigned B0 = cvtpk(p[4],p[5]),  B1 = cvtpk(p[6],p[7]);                    \
    asm("v_permlane32_swap_b32 %0, %1" : "+v"(A0), "+v"(B0));                  \
    asm("v_permlane32_swap_b32 %0, %1" : "+v"(A1), "+v"(B1));                  \
    unsigned C0 = cvtpk(p[8],p[9]),  C1 = cvtpk(p[10],p[11]);                  \
    unsigned D0 = cvtpk(p[12],p[13]),D1 = cvtpk(p[14],p[15]);                  \
    asm("v_permlane32_swap_b32 %0, %1" : "+v"(C0), "+v"(D0));                  \
    asm("v_permlane32_swap_b32 %0, %1" : "+v"(C1), "+v"(D1));                  \
    u32x4 w1 = {A0, A1, B0, B1}, w2 = {C0, C1, D0, D1};                        \
    s16x8 pa1 = __builtin_bit_cast(s16x8, w1);                                 \
    s16x8 pa2 = __builtin_bit_cast(s16x8, w2);                                 \
    O0 = mfma32(pa1, v0, O0); O0 = mfma32(pa2, v1, O0);                        \
    O1 = mfma32(pa1, v2, O1); O1 = mfma32(pa2, v3, O1);                        \
  }

  STAGEK(0, 0);
  __builtin_amdgcn_sched_barrier(0);
  LOADV(0);
  asm volatile("s_waitcnt vmcnt(4)" ::: "memory");
  __syncthreads();
  int cur = 0;
  for (int t = 0; t < 32; ++t){
    if (t < 31){
      STAGEK(cur^1, t+1);
      __builtin_amdgcn_sched_barrier(0);
    }
    COMPUTE(cur);
    if (t < 31){
      LOADV(t+1);
      asm volatile("s_waitcnt vmcnt(4)" ::: "memory");
    }
    __syncthreads();
    cur ^= 1;
  }
  #undef STAGEK
  #undef LOADV
  #undef COMPUTE

  // per-stream l per q-row (valid in all lanes after swap)
  float ts = (lacc[0]+lacc[1]) + (lacc[2]+lacc[3]);
  float tu = ts, tv = ts;
  asm("v_permlane32_swap_b32 %0, %1" : "+v"(tu), "+v"(tv));
  float lrun = tu + tv;

  // ---- 4-way combine (plain sums): streams 0-2 park O as bf16 in their own dead
  // staging region (8KB = 64 rows x 64 cols); stream 3 merges. ----
  if (kvh < 3){
    ushort* park = &ldsK[kvh][0][0];
    #pragma unroll
    for (int g = 0; g < 4; ++g)
      #pragma unroll
      for (int r4 = 0; r4 < 4; ++r4){
        int fr = qg*32 + g*8 + hi*4 + r4;
        park[fr*64 + l31]      = f2b(O0[g*4+r4]);
        park[fr*64 + l31 + 32] = f2b(O1[g*4+r4]);
      }
    if (hi == 0) llds[kvh][qg*32 + l31] = lrun;
  }
  __syncthreads();
  if (kvh == 3){
    if (hi == 0){
      int idx = qg*32 + l31;
      winv[idx] = 1.0f / (llds[0][idx] + llds[1][idx] + llds[2][idx] + lrun);
    }
    asm volatile("s_waitcnt lgkmcnt(0)" ::: "memory");
    const ushort* p0 = &ldsK[0][0][0];
    const ushort* p1 = &ldsK[1][0][0];
    const ushort* p2 = &ldsK[2][0][0];
    size_t colBase = (size_t)b1*64 + l31;
    #pragma unroll
    for (int g = 0; g < 4; ++g){
      f32x4 iv = *reinterpret_cast<const f32x4*>(&winv[qg*32 + g*8 + hi*4]);
      #pragma unroll
      for (int r4 = 0; r4 < 4; ++r4){
        int row = g*8 + hi*4 + r4;
        int fr = qg*32 + row;
        float o0 = (b2f(p0[fr*64 + l31]) + b2f(p1[fr*64 + l31])
                  + b2f(p2[fr*64 + l31]) + O0[g*4+r4]) * iv[r4];
        float o1 = (b2f(p0[fr*64 + l31 + 32]) + b2f(p1[fr*64 + l31 + 32])
                  + b2f(p2[fr*64 + l31 + 32]) + O1[g*4+r4]) * iv[r4];
        size_t base = ((size_t)(hh*512 + a0 + row))*CHN + colBase;
        attnT[base]      = f2b(o0);
        attnT[base + 32] = f2b(o1);
      }
    }
  }
}

extern "C" void kernel_launch(void* const* d_in, const int* in_sizes, int n_in,
                              void* d_out, int out_size, void* d_ws, size_t ws_size,
                              hipStream_t stream)
{
  (void)in_sizes; (void)n_in; (void)out_size; (void)ws_size;
  const float* x     = (const float*)d_in[0];
  const float* normw = (const float*)d_in[1];
  const float* normb = (const float*)d_in[2];
  const float* qkvw  = (const float*)d_in[3];
  const float* qkvb  = (const float*)d_in[4];
  const float* projw = (const float*)d_in[5];
  const float* projb = (const float*)d_in[6];
  float* out = (float*)d_out;

  char* w = (char*)d_ws;
  ushort* h_t  = (ushort*)(w + 1024);                              // 4 MB ; aliased as attnT
  ushort* Wq   = (ushort*)(w + 1024 + 4194304);                    // 1.5 MB
  ushort* Wp   = (ushort*)(w + 1024 + 4194304 + 1572864);          // 0.5 MB
  ushort* qSb  = (ushort*)(w + 1024 + 4194304 + 1572864 + 524288); // 4 MB
  ushort* kFb  = qSb + 2097152;                                    // 4 MB (frag-major)
  ushort* vFb  = kFb + 2097152;                                    // 4 MB (frag-major)
  float*  part = (float*)(vFb + 2097152);                          // 2 KB (no alias)
  ushort* attnT = h_t;

  prep<<<1280, 256, 0, stream>>>((const float4*)qkvw, (const float4*)projw, x,
                                 (ushort4*)Wq, (ushort4*)Wp, part);
  norm_apply<<<512, 256, 0, stream>>>(x, part, normw, normb, h_t);
  gemm_tn<0,128,64><<<dim3(32, 24), 256, 0, stream>>>(h_t, Wq, qkvb, nullptr, qSb, kFb, vFb, nullptr);
  flash9<<<512, 512, 0, stream>>>(qSb, kFb, vFb, attnT);
  gemm_tn<1,64,64><<<dim3(64, 8), 256, 0, stream>>>(attnT, Wp, projb, x, nullptr, nullptr, nullptr, out);
}

// Round 17
// 82.709 us; speedup vs baseline: 1.0879x; 1.0172x over previous
//
#include <hip/hip_runtime.h>

typedef __attribute__((ext_vector_type(8)))  short s16x8;
typedef __attribute__((ext_vector_type(4)))  float f32x4;
typedef __attribute__((ext_vector_type(16))) float f32x16;
typedef __attribute__((ext_vector_type(4)))  unsigned int u32x4;

#define CHN 512
#define NSP 4096

__device__ __forceinline__ ushort f2b(float f){
  unsigned u = __builtin_bit_cast(unsigned, f);
  u = (u + 0x7fffu + ((u >> 16) & 1u)) >> 16;
  return (ushort)u;
}
__device__ __forceinline__ float b2f(ushort u){
  return __builtin_bit_cast(float, ((unsigned)u) << 16);
}

__device__ __forceinline__ s16x8 ldfrag(const void* p){
  return *reinterpret_cast<const s16x8*>(p);
}

__device__ __forceinline__ f32x4 mfma16(s16x8 a, s16x8 b, f32x4 c){
  return __builtin_amdgcn_mfma_f32_16x16x32_bf16(a, b, c, 0, 0, 0);
}
__device__ __forceinline__ f32x16 mfma32(s16x8 a, s16x8 b, f32x16 c){
  return __builtin_amdgcn_mfma_f32_32x32x16_bf16(a, b, c, 0, 0, 0);
}
__device__ __forceinline__ unsigned cvtpk(float lo, float hi){
  unsigned r;
  asm("v_cvt_pk_bf16_f32 %0, %1, %2" : "=v"(r) : "v"(lo), "v"(hi));
  return r;
}
__device__ __forceinline__ void gload16(const void* g, void* l){
  __builtin_amdgcn_global_load_lds(
      (const __attribute__((address_space(1))) unsigned int*)g,
      (__attribute__((address_space(3))) unsigned int*)l, 16, 0, 0);
}
__device__ __forceinline__ ushort4 f4b(float4 v){
  ushort4 o;
  o.x = f2b(v.x); o.y = f2b(v.y); o.z = f2b(v.z); o.w = f2b(v.w);
  return o;
}

// ---------- fused preprocessing: weight cvt (qkv, proj) + group-norm partials ----------
__global__ __launch_bounds__(256) void prep(const float4* __restrict__ qkvw, const float4* __restrict__ projw,
                                            const float* __restrict__ x,
                                            ushort4* __restrict__ Wq, ushort4* __restrict__ Wp,
                                            float* __restrict__ part){
  int b = blockIdx.x;
  if (b < 768){
    int i = b*256 + threadIdx.x;
    Wq[i] = f4b(qkvw[i]);
  } else if (b < 1024){
    int i = (b-768)*256 + threadIdx.x;
    Wp[i] = f4b(projw[i]);
  } else {
    int pb = b - 1024;
    const float4* p = reinterpret_cast<const float4*>(x + (size_t)pb * 8192);
    float s = 0.f, s2 = 0.f;
    #pragma unroll
    for (int i = 0; i < 8; ++i){
      float4 v = p[threadIdx.x + i*256];
      s  += v.x + v.y + v.z + v.w;
      s2 += v.x*v.x + v.y*v.y + v.z*v.z + v.w*v.w;
    }
    #pragma unroll
    for (int off = 32; off > 0; off >>= 1){ s += __shfl_down(s, off); s2 += __shfl_down(s2, off); }
    __shared__ float ls[4], ls2[4];
    int wv = threadIdx.x >> 6;
    if ((threadIdx.x & 63) == 0){ ls[wv] = s; ls2[wv] = s2; }
    __syncthreads();
    if (threadIdx.x == 0){
      part[pb*2]     = ls[0]+ls[1]+ls[2]+ls[3];
      part[pb*2 + 1] = ls2[0]+ls2[1]+ls2[2]+ls2[3];
    }
  }
}

// ---------- fused gn-final + norm + SiLU + transpose: x (C,N) fp32 -> h_t (N,C) bf16 ----------
__global__ __launch_bounds__(256) void norm_apply(const float* __restrict__ x, const float* __restrict__ part,
                                                  const float* __restrict__ nw, const float* __restrict__ nb,
                                                  ushort* __restrict__ h_t){
  __shared__ float tile[64][65];
  __shared__ float smu[32], srs[32];
  if (threadIdx.x < 32){
    int g = threadIdx.x;
    float s = 0.f, s2 = 0.f;
    #pragma unroll
    for (int i = 0; i < 8; ++i){ s += part[(g*8+i)*2]; s2 += part[(g*8+i)*2+1]; }
    float mu  = s * (1.f/65536.f);
    float var = s2 * (1.f/65536.f) - mu*mu;
    smu[g] = mu;
    srs[g] = rsqrtf(var + 1e-5f);
  }
  __syncthreads();
  int ct0 = (blockIdx.x >> 6) << 6;
  int nt0 = (blockIdx.x & 63) << 6;
  int tc = threadIdx.x >> 6;
  int tn = threadIdx.x & 63;
  #pragma unroll
  for (int rr = 0; rr < 16; ++rr){
    int cl = rr*4 + tc;
    int c  = ct0 + cl;
    float v  = x[(size_t)c * NSP + nt0 + tn];
    float hn = (v - smu[c >> 4]) * srs[c >> 4] * nw[c] + nb[c];
    float sv = hn / (1.f + __expf(-hn));
    tile[tn][cl] = sv;
  }
  __syncthreads();
  #pragma unroll
  for (int rr = 0; rr < 16; ++rr){
    int nl = rr*4 + tc;
    h_t[(size_t)(nt0 + nl) * CHN + ct0 + tn] = f2b(tile[nl][tn]);
  }
}

// ---------- GEMM: C(n,o) = A(n,c) * Bw(o,c)^T ----------
// 4-buffer ring + counted vmcnt (T4): stage(k+3) issued at iter k; before the
// barrier wait vmcnt(2*NL) -> stage(k+1) proven landed, stages k+2/k+3 in flight.
// Each stage gets ~3 iterations of latency shadow (vs <1 with vmcnt(0)).
// Slot swizzle (R16): linear LDS dest, global source slot ^= row&3, same XOR on reads.
template<int MODE, int BM, int BN>
__global__ __launch_bounds__(256) void gemm_tn(
    const ushort* __restrict__ A, const ushort* __restrict__ Bw,
    const float* __restrict__ bias, const float* __restrict__ xres,
    ushort* __restrict__ qS, ushort* __restrict__ kF, ushort* __restrict__ vF,
    float* __restrict__ outF)
{
  constexpr int RW = BM/2, CW = BN/2;
  constexpr int MI = RW/16, NJ = CW/16;
  constexpr int NL = BM/64 + BN/64;       // gloads per stage
  __shared__ __align__(16) ushort As[4][BM*32];
  __shared__ __align__(16) ushort Bs[4][BN*32];
  int tid = threadIdx.x;
  int lane = tid & 63, wv = tid >> 6;
  int lr = lane & 15, lg = lane >> 4;
  int wr = wv >> 1, wc = wv & 1;
  int nbB = blockIdx.x * BM;
  int obB = blockIdx.y * BN;
  int nb = nbB + wr*RW, ob = obB + wc*CW;
  f32x4 acc[MI][NJ] = {};

  int sswz = (tid & 3) ^ ((tid >> 2) & 3);
  const ushort* Ag = A  + (size_t)(nbB + (tid>>2))*CHN + sswz*8;
  const ushort* Bg = Bw + (size_t)(obB + (tid>>2))*CHN + sswz*8;
  int rdswz = (lg ^ (lr & 3)) * 8;

  #define GSTAGE(BUF, KK) {                                                    \
    _Pragma("unroll") for (int ii = 0; ii < BM/64; ++ii)                       \
      gload16(Ag + (size_t)ii*64*CHN + (KK), &As[BUF][ii*2048 + tid*8]);       \
    _Pragma("unroll") for (int ii = 0; ii < BN/64; ++ii)                       \
      gload16(Bg + (size_t)ii*64*CHN + (KK), &Bs[BUF][ii*2048 + tid*8]); }

  #define VWAIT() {                                                            \
    if (NL == 3)      asm volatile("s_waitcnt vmcnt(6)" ::: "memory");         \
    else              asm volatile("s_waitcnt vmcnt(4)" ::: "memory"); }

  GSTAGE(0, 0);
  GSTAGE(1, 32);
  GSTAGE(2, 64);
  VWAIT();                 // stage(0) landed; stages 1,2 in flight
  __syncthreads();
  for (int ks = 0; ks < 16; ++ks){
    if (ks + 3 < 16) GSTAGE((ks+3)&3, (ks+3)*32);
    int cb = ks & 3;
    s16x8 af[MI], bf[NJ];
    #pragma unroll
    for (int t = 0; t < MI; ++t) af[t] = *(const s16x8*)&As[cb][(wr*RW + lr + t*16)*32 + rdswz];
    #pragma unroll
    for (int t = 0; t < NJ; ++t) bf[t] = *(const s16x8*)&Bs[cb][(wc*CW + lr + t*16)*32 + rdswz];
    #pragma unroll
    for (int i = 0; i < MI; ++i)
      #pragma unroll
      for (int j = 0; j < NJ; ++j)
        acc[i][j] = mfma16(af[i], bf[j], acc[i][j]);
    VWAIT();               // stage(ks+1) landed; ks+2, ks+3 keep flying
    __syncthreads();
  }
  #undef GSTAGE
  #undef VWAIT

  if (MODE == 0){
    #pragma unroll
    for (int j = 0; j < NJ; ++j){
      int o = ob + j*16 + lr;
      float bs = bias[o];
      int sec = o >> 9;        // 0=Q 1=K 2=V  (uniform per wave)
      int co  = o & 511;
      int bb = co >> 6, dd = co & 63;
      if (sec == 0){
        const float qsc = 0.18033688011112042f;  // 0.125*log2(e)
        #pragma unroll
        for (int i = 0; i < MI; ++i){
          int n0 = nb + i*16 + lg*4;
          int hh = n0 >> 9, aa = n0 & 511;
          size_t base = ((size_t)((hh<<3)+bb)*512 + aa)*64 + dd;
          #pragma unroll
          for (int r = 0; r < 4; ++r)
            qS[base + (size_t)r*64] = f2b((acc[i][j][r] + bs) * qsc);
        }
      } else if (sec == 1){
        int s = dd >> 4, khi = (dd >> 3) & 1, off = dd & 7;
        #pragma unroll
        for (int i = 0; i < MI; ++i){
          int n0 = nb + i*16 + lg*4;
          int hh = n0 >> 9, aa = n0 & 511;
          int T = bb*16 + (aa >> 5);
          size_t widx = ((((size_t)hh*128 + T)*4 + s)*64 + (aa & 31) + 32*khi)*8 + off;
          #pragma unroll
          for (int r = 0; r < 4; ++r)
            kF[widx + (size_t)r*8] = f2b(acc[i][j][r] + bs);
        }
      } else {
        int l31v = dd & 31, fh = dd >> 5;
        #pragma unroll
        for (int i = 0; i < MI; ++i){
          int n0 = nb + i*16 + lg*4;
          int hh = n0 >> 9, aa = n0 & 511;
          int T = bb*16 + (aa >> 5);
          int w = aa & 31;
          int f = fh*2 + (w >> 4);
          int vhi = (w >> 3) & 1, koff = w & 7;
          size_t widx = ((((size_t)hh*128 + T)*4 + f)*64 + l31v + 32*vhi)*8 + koff;
          ushort4 pk;
          pk.x = f2b(acc[i][j][0] + bs);
          pk.y = f2b(acc[i][j][1] + bs);
          pk.z = f2b(acc[i][j][2] + bs);
          pk.w = f2b(acc[i][j][3] + bs);
          *reinterpret_cast<ushort4*>(vF + widx) = pk;
        }
      }
    }
  } else {
    #pragma unroll
    for (int j = 0; j < NJ; ++j){
      int o = ob + j*16 + lr;
      float bs = bias[o];
      #pragma unroll
      for (int i = 0; i < MI; ++i){
        int n0 = nb + i*16 + lg*4;
        f32x4 xr = *reinterpret_cast<const f32x4*>(xres + (size_t)o*NSP + n0);
        f32x4 ov;
        #pragma unroll
        for (int r = 0; r < 4; ++r) ov[r] = acc[i][j][r] + bs + xr[r];
        *reinterpret_cast<f32x4*>(outF + (size_t)o*NSP + n0) = ov;
      }
    }
  }
}

// ---------- flash attention v9 (verified 48.6-48.9us): V direct-to-reg, K-only LDS, counted vmcnt ----------
__global__ __launch_bounds__(512) void flash9(
    const ushort* __restrict__ qS, const ushort* __restrict__ kF,
    const ushort* __restrict__ vF, ushort* __restrict__ attnT)
{
  __shared__ __align__(16) ushort ldsK[4][2][2048];   // [kvh][buf][4KB K tile] = 32KB
  __shared__ __align__(16) float llds[3][64];
  __shared__ __align__(16) float winv[64];
  int lane = threadIdx.x & 63, wv = threadIdx.x >> 6;
  int l31 = lane & 31, hi = lane >> 5;
  int qg = wv & 1, kvh = wv >> 1;
  // bijective XCD swizzle: 512 blocks, 64/XCD -> one head per XCD
  int bx = (blockIdx.x & 7) * 64 + (blockIdx.x >> 3);
  int hh    = bx >> 6;
  int b1    = (bx >> 3) & 7;
  int chunk = bx & 7;
  int a0 = chunk * 64 + qg * 32;

  const ushort* qp = qS + ((size_t)((hh*8 + b1)*512) + a0 + l31)*64 + hi*8;
  s16x8 qf0 = ldfrag(qp), qf1 = ldfrag(qp+16), qf2 = ldfrag(qp+32), qf3 = ldfrag(qp+48);

  f32x16 O0 = {}, O1 = {};
  f32x4 lacc = {};
  s16x8 v0, v1, v2, v3;

  size_t tbase = (size_t)hh*262144 + (size_t)(kvh*32)*2048;

  // stream's 2 waves split the 4KB K tile (wave-uniform LDS base + lane*16B: m104-safe)
  #define STAGEK(BUF, T) {                                                     \
    const ushort* ks_ = kF + tbase + (size_t)(T)*2048 + qg*1024 + lane*8;      \
    ushort* lk_ = &ldsK[kvh][BUF][qg*1024 + lane*8];                           \
    gload16(ks_,       lk_);                                                   \
    gload16(ks_ + 512, lk_ + 512); }

  #define LOADV(T) {                                                           \
    const ushort* vp_ = vF + tbase + (size_t)(T)*2048 + lane*8;                \
    v0 = ldfrag(vp_);        v1 = ldfrag(vp_ + 512);                           \
    v2 = ldfrag(vp_ + 1024); v3 = ldfrag(vp_ + 1536); }

  #define COMPUTE(BUF) {                                                       \
    const ushort* kc = &ldsK[kvh][BUF][lane*8];                                \
    s16x8 k0 = *(const s16x8*)(kc),        k1 = *(const s16x8*)(kc +  512);    \
    s16x8 k2 = *(const s16x8*)(kc + 1024), k3 = *(const s16x8*)(kc + 1536);    \
    f32x16 S = {};                                                             \
    S = mfma32(k0, qf0, S); S = mfma32(k1, qf1, S);                            \
    S = mfma32(k2, qf2, S); S = mfma32(k3, qf3, S);                            \
    float p[16];                                                               \
    _Pragma("unroll") for (int r = 0; r < 16; ++r)                             \
      p[r] = __builtin_amdgcn_exp2f(S[r]);                                     \
    lacc[0] += (p[0]+p[1])   + (p[2]+p[3]);                                    \
    lacc[1] += (p[4]+p[5])   + (p[6]+p[7]);                                    \
    lacc[2] += (p[8]+p[9])   + (p[10]+p[11]);                                  \
    lacc[3] += (p[12]+p[13]) + (p[14]+p[15]);                                  \
    unsigned A0 = cvtpk(p[0],p[1]),  A1 = cvtpk(p[2],p[3]);                    \
    unsigned B0 = cvtpk(p[4],p[5]),  B1 = cvtpk(p[6],p[7]);                    \
    asm("v_permlane32_swap_b32 %0, %1" : "+v"(A0), "+v"(B0));                  \
    asm("v_permlane32_swap_b32 %0, %1" : "+v"(A1), "+v"(B1));                  \
    unsigned C0 = cvtpk(p[8],p[9]),  C1 = cvtpk(p[10],p[11]);                  \
    unsigned D0 = cvtpk(p[12],p[13]),D1 = cvtpk(p[14],p[15]);                  \
    asm("v_permlane32_swap_b32 %0, %1" : "+v"(C0), "+v"(D0));                  \
    asm("v_permlane32_swap_b32 %0, %1" : "+v"(C1), "+v"(D1));                  \
    u32x4 w1 = {A0, A1, B0, B1}, w2 = {C0, C1, D0, D1};                        \
    s16x8 pa1 = __builtin_bit_cast(s16x8, w1);                                 \
    s16x8 pa2 = __builtin_bit_cast(s16x8, w2);                                 \
    O0 = mfma32(pa1, v0, O0); O0 = mfma32(pa2, v1, O0);                        \
    O1 = mfma32(pa1, v2, O1); O1 = mfma32(pa2, v3, O1);                        \
  }

  STAGEK(0, 0);
  __builtin_amdgcn_sched_barrier(0);
  LOADV(0);
  asm volatile("s_waitcnt vmcnt(4)" ::: "memory");
  __syncthreads();
  int cur = 0;
  for (int t = 0; t < 32; ++t){
    if (t < 31){
      STAGEK(cur^1, t+1);
      __builtin_amdgcn_sched_barrier(0);
    }
    COMPUTE(cur);
    if (t < 31){
      LOADV(t+1);
      asm volatile("s_waitcnt vmcnt(4)" ::: "memory");
    }
    __syncthreads();
    cur ^= 1;
  }
  #undef STAGEK
  #undef LOADV
  #undef COMPUTE

  // per-stream l per q-row (valid in all lanes after swap)
  float ts = (lacc[0]+lacc[1]) + (lacc[2]+lacc[3]);
  float tu = ts, tv = ts;
  asm("v_permlane32_swap_b32 %0, %1" : "+v"(tu), "+v"(tv));
  float lrun = tu + tv;

  // ---- 4-way combine (plain sums): streams 0-2 park O as bf16 in their own dead
  // staging region (8KB = 64 rows x 64 cols); stream 3 merges. ----
  if (kvh < 3){
    ushort* park = &ldsK[kvh][0][0];
    #pragma unroll
    for (int g = 0; g < 4; ++g)
      #pragma unroll
      for (int r4 = 0; r4 < 4; ++r4){
        int fr = qg*32 + g*8 + hi*4 + r4;
        park[fr*64 + l31]      = f2b(O0[g*4+r4]);
        park[fr*64 + l31 + 32] = f2b(O1[g*4+r4]);
      }
    if (hi == 0) llds[kvh][qg*32 + l31] = lrun;
  }
  __syncthreads();
  if (kvh == 3){
    if (hi == 0){
      int idx = qg*32 + l31;
      winv[idx] = 1.0f / (llds[0][idx] + llds[1][idx] + llds[2][idx] + lrun);
    }
    asm volatile("s_waitcnt lgkmcnt(0)" ::: "memory");
    const ushort* p0 = &ldsK[0][0][0];
    const ushort* p1 = &ldsK[1][0][0];
    const ushort* p2 = &ldsK[2][0][0];
    size_t colBase = (size_t)b1*64 + l31;
    #pragma unroll
    for (int g = 0; g < 4; ++g){
      f32x4 iv = *reinterpret_cast<const f32x4*>(&winv[qg*32 + g*8 + hi*4]);
      #pragma unroll
      for (int r4 = 0; r4 < 4; ++r4){
        int row = g*8 + hi*4 + r4;
        int fr = qg*32 + row;
        float o0 = (b2f(p0[fr*64 + l31]) + b2f(p1[fr*64 + l31])
                  + b2f(p2[fr*64 + l31]) + O0[g*4+r4]) * iv[r4];
        float o1 = (b2f(p0[fr*64 + l31 + 32]) + b2f(p1[fr*64 + l31 + 32])
                  + b2f(p2[fr*64 + l31 + 32]) + O1[g*4+r4]) * iv[r4];
        size_t base = ((size_t)(hh*512 + a0 + row))*CHN + colBase;
        attnT[base]      = f2b(o0);
        attnT[base + 32] = f2b(o1);
      }
    }
  }
}

extern "C" void kernel_launch(void* const* d_in, const int* in_sizes, int n_in,
                              void* d_out, int out_size, void* d_ws, size_t ws_size,
                              hipStream_t stream)
{
  (void)in_sizes; (void)n_in; (void)out_size; (void)ws_size;
  const float* x     = (const float*)d_in[0];
  const float* normw = (const float*)d_in[1];
  const float* normb = (const float*)d_in[2];
  const float* qkvw  = (const float*)d_in[3];
  const float* qkvb  = (const float*)d_in[4];
  const float* projw = (const float*)d_in[5];
  const float* projb = (const float*)d_in[6];
  float* out = (float*)d_out;

  char* w = (char*)d_ws;
  ushort* h_t  = (ushort*)(w + 1024);                              // 4 MB ; aliased as attnT
  ushort* Wq   = (ushort*)(w + 1024 + 4194304);                    // 1.5 MB
  ushort* Wp   = (ushort*)(w + 1024 + 4194304 + 1572864);          // 0.5 MB
  ushort* qSb  = (ushort*)(w + 1024 + 4194304 + 1572864 + 524288); // 4 MB
  ushort* kFb  = qSb + 2097152;                                    // 4 MB (frag-major)
  ushort* vFb  = kFb + 2097152;                                    // 4 MB (frag-major)
  float*  part = (float*)(vFb + 2097152);                          // 2 KB (no alias)
  ushort* attnT = h_t;

  prep<<<1280, 256, 0, stream>>>((const float4*)qkvw, (const float4*)projw, x,
                                 (ushort4*)Wq, (ushort4*)Wp, part);
  norm_apply<<<512, 256, 0, stream>>>(x, part, normw, normb, h_t);
  gemm_tn<0,128,64><<<dim3(32, 24), 256, 0, stream>>>(h_t, Wq, qkvb, nullptr, qSb, kFb, vFb, nullptr);
  flash9<<<512, 512, 0, stream>>>(qSb, kFb, vFb, attnT);
  gemm_tn<1,64,64><<<dim3(64, 8), 256, 0, stream>>>(attnT, Wp, projb, x, nullptr, nullptr, nullptr, out);
}